// Round 1
// baseline (393.418 us; speedup 1.0000x reference)
//
#include <hip/hip_runtime.h>

// VQ-VAE forward on MI355X, fp32 (no fp32 MFMA on CDNA4 -> vector ALU).
// N = 65536 rows, IN_DIM=256, D=64, K=512.
// ws layout:
//   z:      float[N*64]   @ 0          (64 MB)
//   idx:    int[N]        @ 67108864   (256 KB)
//   sse:    double        @ 67371008
//   counts: int[512]      @ 67371016

#define NROWS 65536

__device__ __forceinline__ unsigned ford(float s) {
    // order-preserving map float -> unsigned (total order, matches < on floats)
    unsigned b = __float_as_uint(s);
    return (b & 0x80000000u) ? ~b : (b | 0x80000000u);
}

// ---------------- K1: z = x @ enc_w  ([N,256]x[256,64]) ----------------
// 2048 blocks x 256 threads; block does 32 rows; enc_w staged in LDS (64 KB).
__global__ __launch_bounds__(256) void k_encode(const float* __restrict__ x,
                                                const float* __restrict__ enc_w,
                                                float* __restrict__ z) {
    __shared__ float wE[256 * 64];  // 64 KB
    int t = threadIdx.x;
    const float4* ew4 = (const float4*)enc_w;
    float4* wE4 = (float4*)wE;
#pragma unroll
    for (int j = 0; j < 16; ++j) wE4[t + 256 * j] = ew4[t + 256 * j];
    __syncthreads();

    int d = t & 63, rg = t >> 6;
    int r0 = blockIdx.x * 32 + rg * 8;   // 8 rows per thread, wave-uniform
    const float4* x4 = (const float4*)x; // x row stride = 64 float4

    float acc[8];
#pragma unroll
    for (int j = 0; j < 8; ++j) acc[j] = 0.f;

    for (int i4 = 0; i4 < 64; ++i4) {
        float w0 = wE[(i4 * 4 + 0) * 64 + d];
        float w1 = wE[(i4 * 4 + 1) * 64 + d];
        float w2 = wE[(i4 * 4 + 2) * 64 + d];
        float w3 = wE[(i4 * 4 + 3) * 64 + d];
#pragma unroll
        for (int j = 0; j < 8; ++j) {
            float4 xv = x4[(r0 + j) * 64 + i4];  // wave-uniform broadcast load
            acc[j] = fmaf(xv.w, w3, fmaf(xv.z, w2, fmaf(xv.y, w1, fmaf(xv.x, w0, acc[j]))));
        }
    }
#pragma unroll
    for (int j = 0; j < 8; ++j) z[(r0 + j) * 64 + d] = acc[j];  // coalesced over d
}

// ---------------- K2: nearest-code assignment + loss/hist ----------------
// 512 blocks x 512 threads; block handles 128 rows; thread t owns codebook row t
// in registers. dist formula mimics reference fp32 rounding: (zz+ee) - 2*dot.
__global__ __launch_bounds__(512) void k_assign(const float* __restrict__ z,
                                                const float* __restrict__ cb,
                                                int* __restrict__ idx,
                                                double* __restrict__ sse,
                                                int* __restrict__ counts) {
    __shared__ float zs[128 * 64];                 // 32 KB z tile
    __shared__ unsigned long long part[128 * 8];   // per-(row,wave) best key, 8 KB
    __shared__ float zzs[128];
    __shared__ int hist[512];

    int t = threadIdx.x;
    int row0 = blockIdx.x * 128;
    hist[t] = 0;

    // stage z tile (coalesced)
    const float4* zg4 = (const float4*)(z + (size_t)row0 * 64);
    float4* zs4 = (float4*)zs;
#pragma unroll
    for (int j = 0; j < 4; ++j) zs4[t + 512 * j] = zg4[t + 512 * j];

    // own codebook row in registers + its squared norm
    const float4* cb4 = (const float4*)cb;
    float4 e4[16];
#pragma unroll
    for (int j = 0; j < 16; ++j) e4[j] = cb4[t * 16 + j];
    float n0 = 0, n1 = 0, n2 = 0, n3 = 0;
#pragma unroll
    for (int j = 0; j < 16; ++j) {
        n0 = fmaf(e4[j].x, e4[j].x, n0);
        n1 = fmaf(e4[j].y, e4[j].y, n1);
        n2 = fmaf(e4[j].z, e4[j].z, n2);
        n3 = fmaf(e4[j].w, e4[j].w, n3);
    }
    float ee = (n0 + n1) + (n2 + n3);
    __syncthreads();

    // per-row ||z||^2
    if (t < 128) {
        float a0 = 0, a1 = 0, a2 = 0, a3 = 0;
#pragma unroll
        for (int j = 0; j < 16; ++j) {
            float4 zv = zs4[t * 16 + j];
            a0 = fmaf(zv.x, zv.x, a0);
            a1 = fmaf(zv.y, zv.y, a1);
            a2 = fmaf(zv.z, zv.z, a2);
            a3 = fmaf(zv.w, zv.w, a3);
        }
        zzs[t] = (a0 + a1) + (a2 + a3);
    }
    __syncthreads();

    int lane = t & 63, wv = t >> 6;
    for (int r = 0; r < 128; ++r) {
        float d0 = 0, d1 = 0, d2 = 0, d3 = 0;
#pragma unroll
        for (int j = 0; j < 16; ++j) {
            float4 zv = zs4[r * 16 + j];  // broadcast read
            float4 ev = e4[j];
            d0 = fmaf(zv.x, ev.x, d0);
            d1 = fmaf(zv.y, ev.y, d1);
            d2 = fmaf(zv.z, ev.z, d2);
            d3 = fmaf(zv.w, ev.w, d3);
        }
        float dot = (d0 + d1) + (d2 + d3);
        float s = (zzs[r] + ee) - 2.0f * dot;  // reference-matching fp32 rounding

        unsigned u = ford(s);
        unsigned m = u, o;
        o = (unsigned)__shfl_xor((int)m, 1);  m = m < o ? m : o;
        o = (unsigned)__shfl_xor((int)m, 2);  m = m < o ? m : o;
        o = (unsigned)__shfl_xor((int)m, 4);  m = m < o ? m : o;
        o = (unsigned)__shfl_xor((int)m, 8);  m = m < o ? m : o;
        o = (unsigned)__shfl_xor((int)m, 16); m = m < o ? m : o;
        o = (unsigned)__shfl_xor((int)m, 32); m = m < o ? m : o;
        unsigned long long bal = __ballot(u == m);
        if (lane == 0) {
            int fl = __ffsll(bal) - 1;  // lowest lane => lowest code index (tie-break)
            part[r * 8 + wv] = ((unsigned long long)m << 32) | (unsigned)((t & ~63) + fl);
        }
    }
    __syncthreads();

    // finalize: per-row best across 8 waves; sse + histogram
    if (t < 128) {
        unsigned long long best = ~0ull;
#pragma unroll
        for (int w = 0; w < 8; ++w) {
            unsigned long long p = part[t * 8 + w];
            best = best < p ? best : p;  // key = (score<<32)|k -> min score, then min k
        }
        int kb = (int)(best & 0xffffffffu);
        idx[row0 + t] = kb;
        atomicAdd(&hist[kb], 1);

        double acc = 0.0;
#pragma unroll
        for (int j = 0; j < 16; ++j) {
            float4 qv = cb4[kb * 16 + j];
            float4 zv = zs4[t * 16 + j];
            float fx = qv.x - zv.x, fy = qv.y - zv.y, fz = qv.z - zv.z, fw = qv.w - zv.w;
            acc += (double)fx * fx + (double)fy * fy + (double)fz * fz + (double)fw * fw;
        }
#pragma unroll
        for (int off = 32; off >= 1; off >>= 1) acc += __shfl_down(acc, off);
        if (lane == 0) atomicAdd(sse, acc);
    }
    __syncthreads();
    if (hist[t]) atomicAdd(&counts[t], hist[t]);
}

// ---------------- K3: x_recon = codebook[idx] @ dec_w ----------------
// 2048 blocks x 256 threads; block does 32 rows; dec_w in LDS; quantized rows
// staged in LDS. out base is d_out+1 (4B-aligned only) -> scalar stores.
__global__ __launch_bounds__(256) void k_decode(const float* __restrict__ cb,
                                                const float* __restrict__ dec_w,
                                                const int* __restrict__ idx,
                                                float* __restrict__ out) {
    __shared__ float wD[64 * 256];  // 64 KB
    __shared__ float qs[32 * 64];   // 8 KB
    __shared__ int lidx[32];

    int t = threadIdx.x;
    int r0 = blockIdx.x * 32;
    const float4* dw4 = (const float4*)dec_w;
    float4* wD4 = (float4*)wD;
#pragma unroll
    for (int j = 0; j < 16; ++j) wD4[t + 256 * j] = dw4[t + 256 * j];
    if (t < 32) lidx[t] = idx[r0 + t];
    __syncthreads();

    {   // stage gathered codebook rows
        int j = t >> 3, c = t & 7;
        const float4* cb4 = (const float4*)cb;
        float4* qs4 = (float4*)qs;
        int kq = lidx[j];
        qs4[j * 16 + c * 2] = cb4[kq * 16 + c * 2];
        qs4[j * 16 + c * 2 + 1] = cb4[kq * 16 + c * 2 + 1];
    }
    __syncthreads();

    int l = t & 63, w = t >> 6;  // wave w -> rows w*8..w*8+7; lane -> 4 columns
    float4 acc[8];
#pragma unroll
    for (int j = 0; j < 8; ++j) acc[j] = make_float4(0.f, 0.f, 0.f, 0.f);

    for (int d = 0; d < 64; ++d) {
        float4 wv = wD4[d * 64 + l];
#pragma unroll
        for (int j = 0; j < 8; ++j) {
            float q = qs[(w * 8 + j) * 64 + d];  // broadcast
            acc[j].x = fmaf(q, wv.x, acc[j].x);
            acc[j].y = fmaf(q, wv.y, acc[j].y);
            acc[j].z = fmaf(q, wv.z, acc[j].z);
            acc[j].w = fmaf(q, wv.w, acc[j].w);
        }
    }
#pragma unroll
    for (int j = 0; j < 8; ++j) {
        int row = r0 + w * 8 + j;
        float* o = out + (size_t)row * 256 + l * 4;
        o[0] = acc[j].x; o[1] = acc[j].y; o[2] = acc[j].z; o[3] = acc[j].w;
    }
}

// ---------------- K4: loss + perplexity scalars ----------------
__global__ __launch_bounds__(512) void k_final(const double* __restrict__ sse,
                                               const int* __restrict__ counts,
                                               float* __restrict__ out_loss,
                                               float* __restrict__ out_pp) {
    __shared__ double red[8];
    int t = threadIdx.x;
    double p = (double)counts[t] / 65536.0;
    double term = p * log(p + 1e-10);
#pragma unroll
    for (int off = 32; off >= 1; off >>= 1) term += __shfl_down(term, off);
    if ((t & 63) == 0) red[t >> 6] = term;
    __syncthreads();
    if (t == 0) {
        double s = 0;
#pragma unroll
        for (int w = 0; w < 8; ++w) s += red[w];
        out_pp[0] = (float)exp(-s);
        out_loss[0] = (float)(1.25 * sse[0] / 4194304.0);  // (1+0.25)*mean((q-z)^2)
    }
}

extern "C" void kernel_launch(void* const* d_in, const int* in_sizes, int n_in,
                              void* d_out, int out_size, void* d_ws, size_t ws_size,
                              hipStream_t stream) {
    const float* x = (const float*)d_in[0];
    const float* enc_w = (const float*)d_in[1];
    const float* dec_w = (const float*)d_in[2];
    const float* cb = (const float*)d_in[3];
    float* out = (float*)d_out;

    char* ws = (char*)d_ws;
    float* z = (float*)ws;                           // 64 MB
    int* idx = (int*)(ws + 67108864);                // 256 KB
    double* sse = (double*)(ws + 67371008);          // 8 B
    int* counts = (int*)(ws + 67371016);             // 2 KB

    // ws is poisoned to 0xAA before each launch -> zero the accumulators
    hipMemsetAsync(ws + 67371008, 0, 8 + 2048, stream);

    k_encode<<<dim3(2048), dim3(256), 0, stream>>>(x, enc_w, z);
    k_assign<<<dim3(512), dim3(512), 0, stream>>>(z, cb, idx, sse, counts);
    k_decode<<<dim3(2048), dim3(256), 0, stream>>>(cb, dec_w, idx, out + 1);
    k_final<<<dim3(1), dim3(512), 0, stream>>>(sse, counts, out, out + 16777217);
}

// Round 2
// 291.623 us; speedup vs baseline: 1.3491x; 1.3491x over previous
//
#include <hip/hip_runtime.h>

// VQ-VAE forward on MI355X, fp32 (no fp32 MFMA on CDNA4 -> vector ALU).
// N = 65536 rows, IN_DIM=256, D=64, K=512.
//
// ws layout (bytes):
//   z:      float[65536*64]  @ 0          (16 MiB)
//   idx:    int[65536]       @ 16777216   (256 KiB)
//   cr:     float[512*256]   @ 17039360   (512 KiB)  = codebook @ dec_w
//   sse:    double           @ 17563648
//   counts: int[512]         @ 17563656

__device__ __forceinline__ unsigned ford(float s) {
    // order-preserving map float -> unsigned (total order, matches < on floats)
    unsigned b = __float_as_uint(s);
    return (b & 0x80000000u) ? ~b : (b | 0x80000000u);
}

__device__ __forceinline__ void gl_lds16(const float4* g, float4* l) {
    __builtin_amdgcn_global_load_lds((const __attribute__((address_space(1))) char*)g,
                                     (__attribute__((address_space(3))) char*)l, 16, 0, 0);
}

// ---------------- K1: z = x @ enc_w  ([65536,256]x[256,64]) ----------------
// 512 blocks x 512 threads; block does 128 rows. K chunked by 64:
// xs tile 32 KB + wE tile 16 KB = 48 KB LDS -> 3 blocks/CU (24 waves/CU).
// x staged via global_load_lds width=16 (per-lane coalesced, lane-contiguous LDS).
__global__ __launch_bounds__(512) void k_encode(const float* __restrict__ x,
                                                const float* __restrict__ enc_w,
                                                float* __restrict__ z) {
    __shared__ float4 xs4[128 * 16];  // [row][k4] current chunk, 32 KB
    __shared__ float wEs[64 * 64];    // [k][d] current chunk, 16 KB

    int t = threadIdx.x;
    int row0 = blockIdx.x * 128;
    int d = t & 63, rg = t >> 6;  // 8 waves; wave rg handles rows rg*16..rg*16+15

    const float4* xg = (const float4*)x;      // x row = 64 float4
    const float4* wg = (const float4*)enc_w;  // 4096 float4 total
    float4* wEs4 = (float4*)wEs;

    float acc[16];
#pragma unroll
    for (int r = 0; r < 16; ++r) acc[r] = 0.f;

    for (int c = 0; c < 4; ++c) {
        // stage x chunk: thread t -> rows (t>>4)+32j, f4 (t&15); LDS f4 off = t+512j
        // (lane-contiguous per wave => satisfies global_load_lds base+lane*16)
#pragma unroll
        for (int j = 0; j < 4; ++j) {
            int lr = (t >> 4) + 32 * j;
            gl_lds16(xg + (size_t)(row0 + lr) * 64 + c * 16 + (t & 15),
                     xs4 + t + 512 * j);
        }
        // stage enc_w chunk (rows c*64..c*64+63, contiguous 1024 f4)
#pragma unroll
        for (int j = 0; j < 2; ++j)
            gl_lds16(wg + c * 1024 + t + 512 * j, wEs4 + t + 512 * j);
        __syncthreads();

        for (int k4 = 0; k4 < 16; ++k4) {
            float w0 = wEs[(k4 * 4 + 0) * 64 + d];  // 2-way bank alias: free
            float w1 = wEs[(k4 * 4 + 1) * 64 + d];
            float w2 = wEs[(k4 * 4 + 2) * 64 + d];
            float w3 = wEs[(k4 * 4 + 3) * 64 + d];
#pragma unroll
            for (int r = 0; r < 16; ++r) {
                float4 xv = xs4[(rg * 16 + r) * 16 + k4];  // LDS broadcast: free
                acc[r] = fmaf(xv.w, w3, fmaf(xv.z, w2, fmaf(xv.y, w1, fmaf(xv.x, w0, acc[r]))));
            }
        }
        __syncthreads();
    }
#pragma unroll
    for (int r = 0; r < 16; ++r)
        z[(size_t)(row0 + rg * 16 + r) * 64 + d] = acc[r];  // coalesced over d
}

// ---------------- K2: nearest-code assignment + loss/hist ----------------
// UNCHANGED numerics (exactly reproduces reference fp32 argmin; do not touch).
__global__ __launch_bounds__(512) void k_assign(const float* __restrict__ z,
                                                const float* __restrict__ cb,
                                                int* __restrict__ idx,
                                                double* __restrict__ sse,
                                                int* __restrict__ counts) {
    __shared__ float zs[128 * 64];                 // 32 KB z tile
    __shared__ unsigned long long part[128 * 8];   // per-(row,wave) best key, 8 KB
    __shared__ float zzs[128];
    __shared__ int hist[512];

    int t = threadIdx.x;
    int row0 = blockIdx.x * 128;
    hist[t] = 0;

    const float4* zg4 = (const float4*)(z + (size_t)row0 * 64);
    float4* zs4 = (float4*)zs;
#pragma unroll
    for (int j = 0; j < 4; ++j) zs4[t + 512 * j] = zg4[t + 512 * j];

    const float4* cb4 = (const float4*)cb;
    float4 e4[16];
#pragma unroll
    for (int j = 0; j < 16; ++j) e4[j] = cb4[t * 16 + j];
    float n0 = 0, n1 = 0, n2 = 0, n3 = 0;
#pragma unroll
    for (int j = 0; j < 16; ++j) {
        n0 = fmaf(e4[j].x, e4[j].x, n0);
        n1 = fmaf(e4[j].y, e4[j].y, n1);
        n2 = fmaf(e4[j].z, e4[j].z, n2);
        n3 = fmaf(e4[j].w, e4[j].w, n3);
    }
    float ee = (n0 + n1) + (n2 + n3);
    __syncthreads();

    if (t < 128) {
        float a0 = 0, a1 = 0, a2 = 0, a3 = 0;
#pragma unroll
        for (int j = 0; j < 16; ++j) {
            float4 zv = zs4[t * 16 + j];
            a0 = fmaf(zv.x, zv.x, a0);
            a1 = fmaf(zv.y, zv.y, a1);
            a2 = fmaf(zv.z, zv.z, a2);
            a3 = fmaf(zv.w, zv.w, a3);
        }
        zzs[t] = (a0 + a1) + (a2 + a3);
    }
    __syncthreads();

    int lane = t & 63, wv = t >> 6;
    for (int r = 0; r < 128; ++r) {
        float d0 = 0, d1 = 0, d2 = 0, d3 = 0;
#pragma unroll
        for (int j = 0; j < 16; ++j) {
            float4 zv = zs4[r * 16 + j];
            float4 ev = e4[j];
            d0 = fmaf(zv.x, ev.x, d0);
            d1 = fmaf(zv.y, ev.y, d1);
            d2 = fmaf(zv.z, ev.z, d2);
            d3 = fmaf(zv.w, ev.w, d3);
        }
        float dot = (d0 + d1) + (d2 + d3);
        float s = (zzs[r] + ee) - 2.0f * dot;  // reference-matching fp32 rounding

        unsigned u = ford(s);
        unsigned m = u, o;
        o = (unsigned)__shfl_xor((int)m, 1);  m = m < o ? m : o;
        o = (unsigned)__shfl_xor((int)m, 2);  m = m < o ? m : o;
        o = (unsigned)__shfl_xor((int)m, 4);  m = m < o ? m : o;
        o = (unsigned)__shfl_xor((int)m, 8);  m = m < o ? m : o;
        o = (unsigned)__shfl_xor((int)m, 16); m = m < o ? m : o;
        o = (unsigned)__shfl_xor((int)m, 32); m = m < o ? m : o;
        unsigned long long bal = __ballot(u == m);
        if (lane == 0) {
            int fl = __ffsll(bal) - 1;  // lowest lane => lowest code index (tie-break)
            part[r * 8 + wv] = ((unsigned long long)m << 32) | (unsigned)((t & ~63) + fl);
        }
    }
    __syncthreads();

    if (t < 128) {
        unsigned long long best = ~0ull;
#pragma unroll
        for (int w = 0; w < 8; ++w) {
            unsigned long long p = part[t * 8 + w];
            best = best < p ? best : p;
        }
        int kb = (int)(best & 0xffffffffu);
        idx[row0 + t] = kb;
        atomicAdd(&hist[kb], 1);

        double acc = 0.0;
#pragma unroll
        for (int j = 0; j < 16; ++j) {
            float4 qv = cb4[kb * 16 + j];
            float4 zv = zs4[t * 16 + j];
            float fx = qv.x - zv.x, fy = qv.y - zv.y, fz = qv.z - zv.z, fw = qv.w - zv.w;
            acc += (double)fx * fx + (double)fy * fy + (double)fz * fz + (double)fw * fw;
        }
#pragma unroll
        for (int off = 32; off >= 1; off >>= 1) acc += __shfl_down(acc, off);
        if (lane == 0) atomicAdd(sse, acc);
    }
    __syncthreads();
    if (hist[t]) atomicAdd(&counts[t], hist[t]);
}

// ---------------- K3a: cr = codebook @ dec_w  ([512,64]x[64,256]) ----------------
// 16 blocks x 256 threads; block does 32 codes; dec_w in LDS.
__global__ __launch_bounds__(256) void k_coderecon(const float* __restrict__ cb,
                                                   const float* __restrict__ dec_w,
                                                   float* __restrict__ cr) {
    __shared__ float wD[64 * 256];  // 64 KB
    __shared__ float qs[32 * 64];   // 8 KB

    int t = threadIdx.x;
    int r0 = blockIdx.x * 32;
    const float4* dw4 = (const float4*)dec_w;
    float4* wD4 = (float4*)wD;
#pragma unroll
    for (int j = 0; j < 16; ++j) wD4[t + 256 * j] = dw4[t + 256 * j];
    {
        const float4* cb4 = (const float4*)cb;
        float4* qs4 = (float4*)qs;
#pragma unroll
        for (int j = 0; j < 2; ++j) qs4[t + 256 * j] = cb4[r0 * 16 + t + 256 * j];
    }
    __syncthreads();

    int l = t & 63, w = t >> 6;  // wave w -> codes w*8..w*8+7; lane -> 4 columns
    float4 acc[8];
#pragma unroll
    for (int j = 0; j < 8; ++j) acc[j] = make_float4(0.f, 0.f, 0.f, 0.f);

    for (int d = 0; d < 64; ++d) {
        float4 wv = wD4[d * 64 + l];
#pragma unroll
        for (int j = 0; j < 8; ++j) {
            float q = qs[(w * 8 + j) * 64 + d];  // broadcast
            acc[j].x = fmaf(q, wv.x, acc[j].x);
            acc[j].y = fmaf(q, wv.y, acc[j].y);
            acc[j].z = fmaf(q, wv.z, acc[j].z);
            acc[j].w = fmaf(q, wv.w, acc[j].w);
        }
    }
    float4* cr4 = (float4*)cr;
#pragma unroll
    for (int j = 0; j < 8; ++j) cr4[(size_t)(r0 + w * 8 + j) * 64 + l] = acc[j];
}

// ---------------- K3b: x_recon[row] = cr[idx[row]] (pure gather) ----------------
// out points at d_out+1 (4B-aligned only) -> dword stores.
__global__ __launch_bounds__(256) void k_gather(const float* __restrict__ cr,
                                                const int* __restrict__ idx,
                                                float* __restrict__ out) {
    int t = threadIdx.x;
    int row = blockIdx.x * 16 + (t >> 4);
    int k = idx[row];
    const float4* cr4 = (const float4*)(cr + (size_t)k * 256);
    float* o = out + (size_t)row * 256;
#pragma unroll
    for (int j = 0; j < 4; ++j) {
        int f4 = (t & 15) + 16 * j;
        float4 v = cr4[f4];
        o[f4 * 4 + 0] = v.x;
        o[f4 * 4 + 1] = v.y;
        o[f4 * 4 + 2] = v.z;
        o[f4 * 4 + 3] = v.w;
    }
}

// ---------------- K4: loss + perplexity scalars ----------------
__global__ __launch_bounds__(512) void k_final(const double* __restrict__ sse,
                                               const int* __restrict__ counts,
                                               float* __restrict__ out_loss,
                                               float* __restrict__ out_pp) {
    __shared__ double red[8];
    int t = threadIdx.x;
    double p = (double)counts[t] / 65536.0;
    double term = p * log(p + 1e-10);
#pragma unroll
    for (int off = 32; off >= 1; off >>= 1) term += __shfl_down(term, off);
    if ((t & 63) == 0) red[t >> 6] = term;
    __syncthreads();
    if (t == 0) {
        double s = 0;
#pragma unroll
        for (int w = 0; w < 8; ++w) s += red[w];
        out_pp[0] = (float)exp(-s);
        out_loss[0] = (float)(1.25 * sse[0] / 4194304.0);  // (1+0.25)*mean((q-z)^2)
    }
}

extern "C" void kernel_launch(void* const* d_in, const int* in_sizes, int n_in,
                              void* d_out, int out_size, void* d_ws, size_t ws_size,
                              hipStream_t stream) {
    const float* x = (const float*)d_in[0];
    const float* enc_w = (const float*)d_in[1];
    const float* dec_w = (const float*)d_in[2];
    const float* cb = (const float*)d_in[3];
    float* out = (float*)d_out;

    char* ws = (char*)d_ws;
    float* z = (float*)ws;                        // 16 MiB
    int* idx = (int*)(ws + 16777216);             // 256 KiB
    float* cr = (float*)(ws + 17039360);          // 512 KiB
    double* sse = (double*)(ws + 17563648);       // 8 B
    int* counts = (int*)(ws + 17563656);          // 2 KiB

    // ws is poisoned to 0xAA before each launch -> zero the accumulators
    hipMemsetAsync(ws + 17563648, 0, 8 + 2048, stream);

    k_coderecon<<<dim3(16), dim3(256), 0, stream>>>(cb, dec_w, cr);
    k_encode<<<dim3(512), dim3(512), 0, stream>>>(x, enc_w, z);
    k_assign<<<dim3(512), dim3(512), 0, stream>>>(z, cb, idx, sse, counts);
    k_gather<<<dim3(4096), dim3(256), 0, stream>>>(cr, idx, out + 1);
    k_final<<<dim3(1), dim3(512), 0, stream>>>(sse, counts, out, out + 16777217);
}